// Round 5
// baseline (271.625 us; speedup 1.0000x reference)
//
#include <hip/hip_runtime.h>
#include <math.h>

#define H 512
#define W 512
#define RM 8
#define TSX 32
#define TSY 32
#define PPT 4                 // vertical pixels per thread
#define LW (TSX + 2*RM)       // 48
#define LH (TSY + 2*RM)       // 48
#define PL (LH * LW)          // 2304 float4 entries = 36.9 KB
#define BIGNEG -200.0f        // finite "masked" bias: ldexp underflow -> exact 0

// software exp2: range-reduce + cubic + ldexp. 7 full-rate VALU ops,
// replaces v_exp_f32 (~32 cy/wave measured across R0-R3 fits). rel err ~8e-4.
__device__ __forceinline__ float exp2_fast(float x) {
    float n = __builtin_rintf(x);          // v_rndne_f32
    float f = x - n;                       // f in [-0.5, 0.5]
    float p = fmaf(f, 0.055504109f, 0.240226507f);
    p = fmaf(f, p, 0.693147181f);
    p = fmaf(f, p, 1.0f);
    return ldexpf(p, (int)n);              // v_cvt_i32_f32 + v_ldexp_f32
}

// one LDS row pass serving centers k in [K0, K1] (compile-time -> zero waste)
template<int K0, int K1>
__device__ __forceinline__ void row_pass(
    const float4* __restrict__ tile, int rb, float jf,
    float r_eff, float Bs,
    const float* bx, const float* Kc,
    const float* c2r, const float* c2g, const float* c2b,
    float* ar, float* ag, float* ab, float* ad)
{
    float ck[PPT];
    #pragma unroll
    for (int k = K0; k <= K1; ++k) {
        float dy  = jf - 8.0f - (float)k;
        float ady = fabsf(dy);
        float by  = (ady <= r_eff) ? Bs * dy * dy : BIGNEG;
        ck[k] = Kc[k] + by;
    }
    #pragma unroll
    for (int i = 0; i <= 2*RM; ++i) {
        float4 s = tile[rb + i];           // ds_read_b128: r,g,b,q
        float qb = s.w + bx[i];            // q = A*(s.s), shared across centers
        #pragma unroll
        for (int k = K0; k <= K1; ++k) {
            float t = fmaf(c2r[k], s.x, qb);
            t = fmaf(c2g[k], s.y, t);
            t = fmaf(c2b[k], s.z, t);
            float w = exp2_fast(t + ck[k]);
            ar[k] = fmaf(w, s.x, ar[k]);
            ag[k] = fmaf(w, s.y, ag[k]);
            ab[k] = fmaf(w, s.z, ab[k]);
            ad[k] += w;
        }
    }
}

// 36.9 KB LDS -> 4 blocks/CU (16 waves); grid 2048 = exactly 2 residency
// passes. launch_bounds(256,4) caps VGPR at 128.
__global__ __launch_bounds__(256, 4) void bilateral_kernel(
    const float* __restrict__ img, const float* __restrict__ params,
    float* __restrict__ out)
{
    __shared__ float4 tile[PL];

    const int n  = blockIdx.z;
    const int x0 = blockIdx.x * TSX;
    const int y0 = blockIdx.y * TSY;

    const float p0 = params[n*3 + 0];
    const float p1 = params[n*3 + 1];
    const float p2 = params[n*3 + 2];
    const int win = ((int)p0) * 14 + 3;     // window = int(p0)*7*2 + 3
    const float r_eff = (float)((win - 1) >> 1);
    const float sc = fmaf(p1, 99.0f, 1.0f);
    const float ss = fmaf(p2, 99.0f, 1.0f);
    const float LOG2E = 1.4426950408889634f;
    // values kept at 0..1 scale; 255^2 and log2(e) folded into A (A < 0)
    const float A  = -65025.0f * LOG2E / (2.0f * sc * sc);
    const float Bs = -LOG2E / (2.0f * ss * ss);

    // ---- stage tile + halo; w-component = q = A*(s.s) ----
    const float* imgN = img + (size_t)n * (3 * H * W);
    for (int idx = threadIdx.x; idx < PL; idx += 256) {
        int ly = idx / LW;
        int lx = idx - ly * LW;
        int gy = y0 + ly - RM; gy = gy < 0 ? 0 : (gy > H-1 ? H-1 : gy);
        int gx = x0 + lx - RM; gx = gx < 0 ? 0 : (gx > W-1 ? W-1 : gx);
        int g = gy * W + gx;
        float vr = imgN[g];
        float vg = imgN[H*W + g];
        float vb = imgN[2*H*W + g];
        tile[idx] = make_float4(vr, vg, vb,
                                A * fmaf(vr, vr, fmaf(vg, vg, vb * vb)));
    }
    __syncthreads();

    const int tx   = threadIdx.x & (TSX - 1);
    const int tq   = threadIdx.x >> 5;      // 0..7
    const int base = tq * PPT;              // center row group

    // per-center constants; K = A*(c.c) comes free from the q plane
    float Kc[PPT], c2r[PPT], c2g[PPT], c2b[PPT];
    float ar[PPT], ag[PPT], ab[PPT], ad[PPT];
    const float m2A = -2.0f * A;
    #pragma unroll
    for (int k = 0; k < PPT; ++k) {
        float4 c = tile[(RM + base + k) * LW + (RM + tx)];
        Kc[k]  = c.w;
        c2r[k] = m2A * c.x;
        c2g[k] = m2A * c.y;
        c2b[k] = m2A * c.z;
        ar[k] = 0.0f; ag[k] = 0.0f; ab[k] = 0.0f; ad[k] = 0.0f;
    }

    // spatial-x bias; masked taps -> BIGNEG -> weight exactly 0
    float bx[2*RM + 1];
    #pragma unroll
    for (int i = 0; i <= 2*RM; ++i) {
        float d  = (float)(i - RM);
        float a_ = fabsf(d);
        bx[i] = (a_ <= r_eff) ? Bs * d * d : BIGNEG;
    }

    #define RB(j) ((base + (j)) * LW + tx)
    // head rows: row j serves centers k <= j only (dy >= -8), zero waste
    row_pass<0,0>(tile, RB(0), 0.0f, r_eff, Bs, bx, Kc, c2r, c2g, c2b, ar, ag, ab, ad);
    row_pass<0,1>(tile, RB(1), 1.0f, r_eff, Bs, bx, Kc, c2r, c2g, c2b, ar, ag, ab, ad);
    row_pass<0,2>(tile, RB(2), 2.0f, r_eff, Bs, bx, Kc, c2r, c2g, c2b, ar, ag, ab, ad);
    // middle rows: all centers active
    #pragma unroll 1
    for (int j = 3; j <= 16; ++j)
        row_pass<0,3>(tile, RB(j), (float)j, r_eff, Bs, bx, Kc, c2r, c2g, c2b, ar, ag, ab, ad);
    // tail rows: row j serves centers k >= j-16 only (dy <= 8)
    row_pass<1,3>(tile, RB(17), 17.0f, r_eff, Bs, bx, Kc, c2r, c2g, c2b, ar, ag, ab, ad);
    row_pass<2,3>(tile, RB(18), 18.0f, r_eff, Bs, bx, Kc, c2r, c2g, c2b, ar, ag, ab, ad);
    row_pass<3,3>(tile, RB(19), 19.0f, r_eff, Bs, bx, Kc, c2r, c2g, c2b, ar, ag, ab, ad);
    #undef RB

    float* outN = out + (size_t)n * (3 * H * W);
    #pragma unroll
    for (int k = 0; k < PPT; ++k) {
        const float inv = __builtin_amdgcn_rcpf(ad[k]);
        const int o = (y0 + base + k) * W + (x0 + tx);
        outN[o]         = ar[k] * inv;
        outN[H*W + o]   = ag[k] * inv;
        outN[2*H*W + o] = ab[k] * inv;
    }
}

extern "C" void kernel_launch(void* const* d_in, const int* in_sizes, int n_in,
                              void* d_out, int out_size, void* d_ws, size_t ws_size,
                              hipStream_t stream) {
    const float* img    = (const float*)d_in[0];
    const float* params = (const float*)d_in[1];
    float* out          = (float*)d_out;
    dim3 grid(W / TSX, H / TSY, 8);
    bilateral_kernel<<<grid, dim3(256), 0, stream>>>(img, params, out);
}

// Round 6
// 237.122 us; speedup vs baseline: 1.1455x; 1.1455x over previous
//
#include <hip/hip_runtime.h>
#include <math.h>

#define H 512
#define W 512
#define RM 8
#define TSX 32
#define TSY 16
#define PPT 2
#define LW (TSX + 2*RM)       // 48 cols
#define LH (TSY + 2*RM)       // 32 rows
#define NP (LW/2)             // 24 pairs per row
#define BIGNEG -200.0f

typedef _Float16 h2 __attribute__((ext_vector_type(2)));
typedef unsigned short u2v __attribute__((ext_vector_type(2)));

struct __align__(16) Pk { h2 r, g, b, q; };   // one ds_read_b128 = 2 taps

__device__ __forceinline__ h2 bcast(float v) {
    _Float16 h = (_Float16)v; h2 r; r.x = h; r.y = h; return r;
}

// packed f16 exp2: magic-add RNE capture + quadratic + exponent bit-add.
// valid for x in [-13, 15.5]; caller clamps low side. rel err ~0.25%.
__device__ __forceinline__ h2 exp2_pk(h2 x) {
    const h2 magic = bcast(1536.0f);          // 1.5 * 2^10
    h2 m = x + magic;                          // n = m - 1536 (exact RNE)
    h2 f = x - (m - magic);                    // f in [-0.5, 0.5]
    h2 p = f * bcast(0.242632f) + bcast(0.703554f);
    p = f * p + bcast(1.0f);
    // bits(m) = 0x6600 + n  ->  (bits(m)<<10) mod 2^16 = n<<10
    u2v wb = __builtin_bit_cast(u2v, p) +
             (u2v)(__builtin_bit_cast(u2v, m) << 10);
    return __builtin_bit_cast(h2, wb);
}

// 12.3 KB LDS; launch_bounds(256,4) caps VGPR at 128 (expect ~60, no spill).
// grid 4096 blocks / (4 blocks/CU * 256 CU) = 4 clean residency passes.
__global__ __launch_bounds__(256, 4) void bilateral_kernel(
    const float* __restrict__ img, const float* __restrict__ params,
    float* __restrict__ out)
{
    __shared__ Pk tile[LH * NP];

    const int n  = blockIdx.z;
    const int x0 = blockIdx.x * TSX;
    const int y0 = blockIdx.y * TSY;

    const float p0 = params[n*3 + 0];
    const float p1 = params[n*3 + 1];
    const float p2 = params[n*3 + 2];
    const int win = ((int)p0) * 14 + 3;       // window = int(p0)*7*2 + 3
    const int r   = (win - 1) >> 1;
    const float sc = fmaf(p1, 99.0f, 1.0f);
    const float ss = fmaf(p2, 99.0f, 1.0f);
    const float LOG2E = 1.4426950408889634f;
    const float A  = -65025.0f * LOG2E / (2.0f * sc * sc);  // A < 0
    const float Bs = -LOG2E / (2.0f * ss * ss);

    // ---- stage tile+halo as packed f16 pairs {r,g,b,q}, q = A*(s.s) ----
    const float* imgN = img + (size_t)n * (3 * H * W);
    for (int idx = threadIdx.x; idx < LH * NP; idx += 256) {
        int row = idx / NP;
        int pc  = idx - row * NP;
        int gy  = y0 + row - RM; gy = gy < 0 ? 0 : (gy > H-1 ? H-1 : gy);
        int gx0 = x0 + 2*pc - RM;
        int gx1 = gx0 + 1;
        gx0 = gx0 < 0 ? 0 : (gx0 > W-1 ? W-1 : gx0);
        gx1 = gx1 < 0 ? 0 : (gx1 > W-1 ? W-1 : gx1);
        int g0 = gy * W + gx0, g1 = gy * W + gx1;
        float r0 = imgN[g0],          r1 = imgN[g1];
        float v0 = imgN[H*W + g0],    v1 = imgN[H*W + g1];
        float b0 = imgN[2*H*W + g0],  b1 = imgN[2*H*W + g1];
        float q0 = A * fmaf(r0, r0, fmaf(v0, v0, b0 * b0));
        float q1 = A * fmaf(r1, r1, fmaf(v1, v1, b1 * b1));
        Pk pk;
        pk.r.x = (_Float16)r0; pk.r.y = (_Float16)r1;
        pk.g.x = (_Float16)v0; pk.g.y = (_Float16)v1;
        pk.b.x = (_Float16)b0; pk.b.y = (_Float16)b1;
        pk.q.x = (_Float16)q0; pk.q.y = (_Float16)q1;
        tile[idx] = pk;
    }
    __syncthreads();

    const int tx   = threadIdx.x & 31;
    const int tq   = threadIdx.x >> 5;        // 0..7 half-wave groups
    const int base = tq * PPT;                // center rows base..base+1
    const int par  = tx & 1;                  // pair parity
    const int p0i  = tx >> 1;                 // first pair of this lane's window

    // per-center constants from the staged tile (K = q of center; K and the
    // +15 exponent shift are uniform per center -> cancel in num/den)
    const float m2A = -2.0f * A;
    h2 c2r[PPT], c2g[PPT], c2b[PPT];
    float Kf[PPT];
    float accr[PPT], accg[PPT], accb[PPT], accd[PPT];
    #pragma unroll
    for (int k = 0; k < PPT; ++k) {
        Pk c = tile[(RM + base + k) * NP + ((tx + RM) >> 1)];
        float cr = (float)(par ? c.r.y : c.r.x);
        float cg = (float)(par ? c.g.y : c.g.x);
        float cb = (float)(par ? c.b.y : c.b.x);
        Kf[k]  = (float)(par ? c.q.y : c.q.x);
        c2r[k] = bcast(m2A * cr);
        c2g[k] = bcast(m2A * cg);
        c2b[k] = bcast(m2A * cb);
        accr[k] = 0.0f; accg[k] = 0.0f; accb[k] = 0.0f; accd[k] = 0.0f;
    }

    // parity-shifted packed spatial-x bias:
    // even lanes: pair j covers dx = (2j-8, 2j-7); odd: (2j-9, 2j-8)
    h2 bxp[9];
    #pragma unroll
    for (int j = 0; j < 9; ++j) {
        int dx0 = 2*j - 8 - par;
        int dx1 = dx0 + 1;
        int a0 = dx0 < 0 ? -dx0 : dx0;
        int a1 = dx1 < 0 ? -dx1 : dx1;
        float f0 = (a0 <= r) ? Bs * (float)(dx0*dx0) : BIGNEG;
        float f1 = (a1 <= r) ? Bs * (float)(dx1*dx1) : BIGNEG;
        bxp[j].x = (_Float16)f0; bxp[j].y = (_Float16)f1;
    }

    const h2 mlo  = bcast(-13.0f);
    const h2 onep = bcast(1.0f);

    #pragma unroll 1
    for (int j = 0; j < 2*RM + PPT; ++j) {    // 18 rows
        h2 ck[PPT];
        #pragma unroll
        for (int k = 0; k < PPT; ++k) {
            int dy  = j - RM - k;             // in [-9, 9]
            int ady = dy < 0 ? -dy : dy;
            float by = (ady <= r) ? Bs * (float)(dy*dy) : BIGNEG;
            ck[k] = bcast(Kf[k] + by + 15.0f);  // +15: exponent headroom shift
        }
        const int rb = (base + j) * NP + p0i;
        #pragma unroll
        for (int jj = 0; jj < 9; ++jj) {
            Pk s = tile[rb + jj];             // ds_read_b128: 2 taps
            h2 qb = s.q + bxp[jj];            // shared across centers
            #pragma unroll
            for (int k = 0; k < PPT; ++k) {
                h2 t = s.r * c2r[k] + qb;     // v_pk_fma_f16 chain
                t = s.g * c2g[k] + t;
                t = s.b * c2b[k] + t;
                t = t + ck[k];
                t = __builtin_elementwise_max(t, mlo);
                h2 w = exp2_pk(t);
                accr[k] = __builtin_amdgcn_fdot2(w, s.r, accr[k], false);
                accg[k] = __builtin_amdgcn_fdot2(w, s.g, accg[k], false);
                accb[k] = __builtin_amdgcn_fdot2(w, s.b, accb[k], false);
                accd[k] = __builtin_amdgcn_fdot2(w, onep, accd[k], false);
            }
        }
    }

    float* outN = out + (size_t)n * (3 * H * W);
    #pragma unroll
    for (int k = 0; k < PPT; ++k) {
        const float inv = __builtin_amdgcn_rcpf(accd[k]);
        const int o = (y0 + base + k) * W + (x0 + tx);
        outN[o]         = accr[k] * inv;
        outN[H*W + o]   = accg[k] * inv;
        outN[2*H*W + o] = accb[k] * inv;
    }
}

extern "C" void kernel_launch(void* const* d_in, const int* in_sizes, int n_in,
                              void* d_out, int out_size, void* d_ws, size_t ws_size,
                              hipStream_t stream) {
    const float* img    = (const float*)d_in[0];
    const float* params = (const float*)d_in[1];
    float* out          = (float*)d_out;
    dim3 grid(W / TSX, H / TSY, 8);
    bilateral_kernel<<<grid, dim3(256), 0, stream>>>(img, params, out);
}